// Round 6
// baseline (38852.197 us; speedup 1.0000x reference)
//
#include <hip/hip_runtime.h>
#include <math.h>

// 2-layer tanh RNN, B=64 T=1024 I=256 H=512, fp32.
//   xp  = x @ W_ih^T + (b_ih + b_hh)      (GEMM, parallel)
//   h_t = tanh(xp_t + h_{t-1} @ W_hh^T)   (sequential scan)
//   out = h2[:,-1,:] @ fc_W^T + fc_b
//
// SCAN: register-resident W_hh, one 1024-thread block per batch element.
// r4 counters showed VALUBusy 11%, 4.9us/step, FETCH 304MB: the per-step IC
// round-trip (store-drain + flag poll + 1MB/step agent-scope exchange loads)
// dominated. This design has NO cross-block communication:
//   grid = 64 blocks (1/batch). Wave w owns j in [32w, 32w+32).
//   Lane l: j = 32w + (l&31), k-half = l>>5, holds W[j][khalf*256..+255]
//   in 256 VGPRs (16 waves x 64 lanes x 256 x 4B = 1MB = all of W_hh).
// Per step: broadcast ds_read_b128 of h (2 addrs/wave), 256 FMA/lane,
// one shfl_xor(32) joins k-halves, tanh on 32 lanes, LDS write, ONE barrier.
// h double-buffered in LDS (2-unrolled loop). 96KB dyn-LDS forces 1 block/CU.
// Cross-chunk h carried via global hstate (kernel boundary = ordering).
//
// Watch in counters: VALUBusy 60-80% => VALU-bound (floor ~0.85us/step);
// ~35-50% + dur 2x floor => LDS-return-path-bound -> next: j-pair x k-quarter
// layout (each h read feeds 2 FMAs). VGPR_Count ~300 expected; 512 => spill.
//
// WS layout: P[C*64*512 f32] | Hc[C*64*512 f32] | hstateA 128KB | hstateB 128KB

#define B_  64
#define T_  1024
#define H_  512

// ------- projection GEMM: Cout[m][512] = A[row(m)][K] @ W[512][K]^T + (bi+bh)
// Row mapping m -> (b = m>>lgC, lt = m&(C-1)), A row = b*Tfull + t0 + lt.
template<int K>
__global__ __launch_bounds__(256)
void proj_gemm(const float* __restrict__ A, const float* __restrict__ W,
               const float* __restrict__ bi, const float* __restrict__ bh,
               float* __restrict__ Cout, int lgC, int t0, int Tfull)
{
    __shared__ float As[32*132];   // [k][m], padded
    __shared__ float Bs[32*68];    // [k][n], padded
    const int tid = threadIdx.x;
    const int m0 = blockIdx.x * 128;
    const int n0 = blockIdx.y * 64;
    const int ty = tid >> 4;
    const int tx = tid & 15;
    const int lr = tid >> 3;
    const int lk = (tid & 7) * 4;
    const int Cm = (1 << lgC) - 1;

    float acc[8][4];
    #pragma unroll
    for (int i = 0; i < 8; ++i)
        #pragma unroll
        for (int j = 0; j < 4; ++j) acc[i][j] = 0.f;

    for (int k0 = 0; k0 < K; k0 += 32) {
        #pragma unroll
        for (int p = 0; p < 4; ++p) {          // A tile 128x32
            int r = p*32 + lr;
            int m = m0 + r;
            int b = m >> lgC, lt = m & Cm;
            size_t row = (size_t)b * Tfull + t0 + lt;
            float4 v = *reinterpret_cast<const float4*>(&A[row*K + k0 + lk]);
            As[(lk+0)*132 + r] = v.x;  As[(lk+1)*132 + r] = v.y;
            As[(lk+2)*132 + r] = v.z;  As[(lk+3)*132 + r] = v.w;
        }
        #pragma unroll
        for (int p = 0; p < 2; ++p) {          // W tile 64x32
            int r = p*32 + lr;
            float4 v = *reinterpret_cast<const float4*>(&W[(size_t)(n0 + r)*K + k0 + lk]);
            Bs[(lk+0)*68 + r] = v.x;  Bs[(lk+1)*68 + r] = v.y;
            Bs[(lk+2)*68 + r] = v.z;  Bs[(lk+3)*68 + r] = v.w;
        }
        __syncthreads();
        #pragma unroll
        for (int k = 0; k < 32; ++k) {
            float4 a0 = *reinterpret_cast<const float4*>(&As[k*132 + ty*8]);
            float4 a1 = *reinterpret_cast<const float4*>(&As[k*132 + ty*8 + 4]);
            float4 bv = *reinterpret_cast<const float4*>(&Bs[k*68 + tx*4]);
            float av[8] = {a0.x,a0.y,a0.z,a0.w,a1.x,a1.y,a1.z,a1.w};
            float bb[4] = {bv.x,bv.y,bv.z,bv.w};
            #pragma unroll
            for (int i = 0; i < 8; ++i)
                #pragma unroll
                for (int j = 0; j < 4; ++j) acc[i][j] += av[i]*bb[j];
        }
        __syncthreads();
    }
    float4 bias;
    bias.x = bi[n0+tx*4+0] + bh[n0+tx*4+0];
    bias.y = bi[n0+tx*4+1] + bh[n0+tx*4+1];
    bias.z = bi[n0+tx*4+2] + bh[n0+tx*4+2];
    bias.w = bi[n0+tx*4+3] + bh[n0+tx*4+3];
    #pragma unroll
    for (int i = 0; i < 8; ++i) {
        int m = m0 + ty*8 + i;
        float4 v = { acc[i][0]+bias.x, acc[i][1]+bias.y,
                     acc[i][2]+bias.z, acc[i][3]+bias.w };
        *reinterpret_cast<float4*>(&Cout[(size_t)m*H_ + n0 + tx*4]) = v;
    }
}

// ------- register-resident recurrent scan, one batch per block -------------
__global__ __launch_bounds__(1024, 4)
void rnn_scan_reg(const float* __restrict__ Whh, const float* __restrict__ xp,
                  float* __restrict__ hist, float* __restrict__ hstate,
                  int t0, int Csteps)
{
    extern __shared__ float lds[];
    float* bufA = lds;          // h, even-step source
    float* bufB = lds + H_;     // h, odd-step source

    const int tid = threadIdx.x;
    const int b   = blockIdx.x;
    const int w   = tid >> 6;
    const int l   = tid & 63;
    const int jl  = l & 31;
    const int kh  = l >> 5;
    const int j   = w * 32 + jl;

    // Load this lane's 256 weights (one-time; L2/L3-served after first touch).
    float wr[256];
    {
        const float* src = &Whh[(size_t)j * H_ + kh * 256];
        #pragma unroll
        for (int c4 = 0; c4 < 64; ++c4) {
            float4 v = *reinterpret_cast<const float4*>(&src[c4 * 4]);
            wr[c4*4+0] = v.x;  wr[c4*4+1] = v.y;
            wr[c4*4+2] = v.z;  wr[c4*4+3] = v.w;
        }
    }
    if (tid < H_) bufA[tid] = (t0 == 0) ? 0.f : hstate[(size_t)b * H_ + tid];
    __syncthreads();

    const size_t xbase = (size_t)b * Csteps;

#define STEP(HR, HW, LT)                                                     \
    {                                                                        \
        float xpv = 0.f;                                                     \
        if (l < 32) xpv = xp[(xbase + (size_t)(LT)) * H_ + j];               \
        const float* hb = (HR) + kh * 256;                                   \
        float a0 = 0.f, a1 = 0.f, a2 = 0.f, a3 = 0.f;                        \
        _Pragma("unroll")                                                    \
        for (int c4 = 0; c4 < 64; ++c4) {                                    \
            float4 hv = *reinterpret_cast<const float4*>(&hb[c4 * 4]);       \
            a0 += wr[c4*4+0] * hv.x;  a1 += wr[c4*4+1] * hv.y;               \
            a2 += wr[c4*4+2] * hv.z;  a3 += wr[c4*4+3] * hv.w;               \
        }                                                                    \
        float part = (a0 + a1) + (a2 + a3);                                  \
        part += __shfl_xor(part, 32, 64);                                    \
        if (l < 32) {                                                        \
            float h = tanhf(part + xpv);                                     \
            (HW)[j] = h;                                                     \
            if (hist) hist[(xbase + (size_t)(LT)) * H_ + j] = h;             \
        }                                                                    \
        __syncthreads();                                                     \
    }

    for (int lt = 0; lt < Csteps; lt += 2) {
        STEP(bufA, bufB, lt);
        STEP(bufB, bufA, lt + 1);
    }
#undef STEP

    // C even -> final h in bufA. Persist for next chunk / FC head.
    if (tid < 128) {
        float4 v = *reinterpret_cast<const float4*>(&bufA[tid * 4]);
        *reinterpret_cast<float4*>(&hstate[(size_t)b * H_ + tid * 4]) = v;
    }
}

// ------- tiny FC head -----------------------------------------------------
__global__ __launch_bounds__(64)
void fc_kernel(const float* __restrict__ hl, const float* __restrict__ fw,
               const float* __restrict__ fb, float* __restrict__ out)
{
    int b = blockIdx.x, tid = threadIdx.x;
    float p0 = 0.f, p1 = 0.f;
    #pragma unroll
    for (int i = 0; i < 8; ++i) {
        int k = tid + i*64;
        float h = hl[(size_t)b*H_ + k];
        p0 += h * fw[k];
        p1 += h * fw[H_ + k];
    }
    #pragma unroll
    for (int off = 32; off > 0; off >>= 1) {
        p0 += __shfl_down(p0, off, 64);
        p1 += __shfl_down(p1, off, 64);
    }
    if (tid == 0) {
        out[b*2+0] = p0 + fb[0];
        out[b*2+1] = p1 + fb[1];
    }
}

extern "C" void kernel_launch(void* const* d_in, const int* in_sizes, int n_in,
                              void* d_out, int out_size, void* d_ws, size_t ws_size,
                              hipStream_t stream)
{
    const float* x    = (const float*)d_in[0];
    const float* Wih0 = (const float*)d_in[1];
    const float* Whh0 = (const float*)d_in[2];
    const float* bih0 = (const float*)d_in[3];
    const float* bhh0 = (const float*)d_in[4];
    const float* Wih1 = (const float*)d_in[5];
    const float* Whh1 = (const float*)d_in[6];
    const float* bih1 = (const float*)d_in[7];
    const float* bhh1 = (const float*)d_in[8];
    const float* fcW  = (const float*)d_in[9];
    const float* fcb  = (const float*)d_in[10];
    float* out = (float*)d_out;

    // ws-adaptive chunk size (ws_size constant per session -> graph-safe).
    const size_t EXTRA = 1u << 20;
    int C = 1024;
    while (C > 16 && (2*(size_t)C*131072 + EXTRA) > ws_size) C >>= 1;
    int lgC = 0; { int t = C; while (t > 1) { t >>= 1; ++lgC; } }

    char* ws = (char*)d_ws;
    size_t S = (size_t)C * 131072;
    float* P       = (float*)ws;          // xp0 then xp1 (per chunk)
    float* Hc      = (float*)(ws + S);    // h1 chunk
    float* hstateA = (float*)(ws + 2*S);           // 128 KB (layer-0 carry)
    float* hstateB = (float*)(ws + 2*S + 131072);  // 128 KB (layer-1 carry = h2 last)

    // 96KB dynamic LDS: we use 4KB, but >80KB forces 1 block/CU so the 64
    // blocks spread across 64 distinct CUs.
    const int SCAN_LDS = 98304;
    hipFuncSetAttribute(reinterpret_cast<const void*>(rnn_scan_reg),
                        hipFuncAttributeMaxDynamicSharedMemorySize, SCAN_LDS);

    const int nch = T_ / C;
    for (int c = 0; c < nch; ++c) {
        const int t0 = c * C;
        // xp0 chunk = x[:, t0:t0+C, :] @ Wih0^T + bias
        proj_gemm<256><<<dim3(C/2, 8), 256, 0, stream>>>(x, Wih0, bih0, bhh0,
                                                         P, lgC, t0, T_);
        // layer-0 scan chunk -> h1 chunk (+ carry in hstateA)
        rnn_scan_reg<<<B_, 1024, SCAN_LDS, stream>>>(Whh0, P, Hc, hstateA, t0, C);
        // xp1 chunk = h1chunk @ Wih1^T + bias (overwrites P)
        proj_gemm<512><<<dim3(C/2, 8), 256, 0, stream>>>(Hc, Wih1, bih1, bhh1,
                                                         P, lgC, 0, C);
        // layer-1 scan chunk; no history needed, carry/final in hstateB
        rnn_scan_reg<<<B_, 1024, SCAN_LDS, stream>>>(Whh1, P, nullptr, hstateB, t0, C);
    }
    fc_kernel<<<64, 64, 0, stream>>>(hstateB, fcW, fcb, out);
}

// Round 8
// 6237.944 us; speedup vs baseline: 6.2284x; 6.2284x over previous
//
#include <hip/hip_runtime.h>
#include <math.h>

// 2-layer tanh RNN, B=64 T=1024 I=256 H=512, fp32.
//   xp  = x @ W_ih^T + (b_ih + b_hh)      (GEMM, parallel)
//   h_t = tanh(xp_t + h_{t-1} @ W_hh^T)   (sequential scan)
//   out = h2[:,-1,:] @ fc_W^T + fc_b
//
// SCAN = r4 structure (LDS-resident W_hh, 8 slices x 64 rows, 32 pairs x 8
// slices = 256 blocks = 1/CU, co-resident) with TAGGED-DATA sync replacing
// flags (r4: 4.9us/step, VALUBusy 11% -- sync chain dominated).
//   Producers store ONE 8B word {tag=step, h} agent-scope (self-publishing:
//   no drain barrier, no flag round-trip). Consumers poll the data words for
//   tag==expected. Monotonic tags => 2-slot ring is WAR-safe (publishing t+2
//   into slot t&1 requires having observed ALL slices at t+1, which requires
//   every block passed consumption of t). 0xAA ws-poison is inert (garbage
//   tag never equals a real tag) -> zero memsets needed.
//   Wave kg polls only its own k-range; own slice self-filled via LDS --
//   EXCEPT at lt==0 of a non-first chunk (LDS fresh): full-poll all 4 words
//   (own slice sits in hxt with tag==base from the previous launch).
//   [r7 audit fix -- previous version dotted garbage at chunk-2 lt=0.]
//
// r6 lesson (VGPR=64 + FETCH 9GB = spill): per-CU VGPR file is 512KB; a
// 16-wave block can never hold 1MB W_hh fp32 in registers. Don't retry.
//
// WS: P[C*64*512 f32] | Hc[same] | h2last 128KB | hxtA 512KB | hxtB 512KB
//     hxt layout: u64[2 parity][64 batch][512 k] = {tag:u32 hi, h:f32 lo}

#define B_  64
#define T_  1024
#define H_  512
#define JS  64      // rows per slice = H_/8

// ------- projection GEMM: Cout[m][512] = A[row(m)][K] @ W[512][K]^T + (bi+bh)
// Row mapping m -> (b = m>>lgC, lt = m&(C-1)), A row = b*Tfull + t0 + lt.
template<int K>
__global__ __launch_bounds__(256)
void proj_gemm(const float* __restrict__ A, const float* __restrict__ W,
               const float* __restrict__ bi, const float* __restrict__ bh,
               float* __restrict__ Cout, int lgC, int t0, int Tfull)
{
    __shared__ float As[32*132];   // [k][m], padded
    __shared__ float Bs[32*68];    // [k][n], padded
    const int tid = threadIdx.x;
    const int m0 = blockIdx.x * 128;
    const int n0 = blockIdx.y * 64;
    const int ty = tid >> 4;
    const int tx = tid & 15;
    const int lr = tid >> 3;
    const int lk = (tid & 7) * 4;
    const int Cm = (1 << lgC) - 1;

    float acc[8][4];
    #pragma unroll
    for (int i = 0; i < 8; ++i)
        #pragma unroll
        for (int j = 0; j < 4; ++j) acc[i][j] = 0.f;

    for (int k0 = 0; k0 < K; k0 += 32) {
        #pragma unroll
        for (int p = 0; p < 4; ++p) {          // A tile 128x32
            int r = p*32 + lr;
            int m = m0 + r;
            int b = m >> lgC, lt = m & Cm;
            size_t row = (size_t)b * Tfull + t0 + lt;
            float4 v = *reinterpret_cast<const float4*>(&A[row*K + k0 + lk]);
            As[(lk+0)*132 + r] = v.x;  As[(lk+1)*132 + r] = v.y;
            As[(lk+2)*132 + r] = v.z;  As[(lk+3)*132 + r] = v.w;
        }
        #pragma unroll
        for (int p = 0; p < 2; ++p) {          // W tile 64x32
            int r = p*32 + lr;
            float4 v = *reinterpret_cast<const float4*>(&W[(size_t)(n0 + r)*K + k0 + lk]);
            Bs[(lk+0)*68 + r] = v.x;  Bs[(lk+1)*68 + r] = v.y;
            Bs[(lk+2)*68 + r] = v.z;  Bs[(lk+3)*68 + r] = v.w;
        }
        __syncthreads();
        #pragma unroll
        for (int k = 0; k < 32; ++k) {
            float4 a0 = *reinterpret_cast<const float4*>(&As[k*132 + ty*8]);
            float4 a1 = *reinterpret_cast<const float4*>(&As[k*132 + ty*8 + 4]);
            float4 bv = *reinterpret_cast<const float4*>(&Bs[k*68 + tx*4]);
            float av[8] = {a0.x,a0.y,a0.z,a0.w,a1.x,a1.y,a1.z,a1.w};
            float bb[4] = {bv.x,bv.y,bv.z,bv.w};
            #pragma unroll
            for (int i = 0; i < 8; ++i)
                #pragma unroll
                for (int j = 0; j < 4; ++j) acc[i][j] += av[i]*bb[j];
        }
        __syncthreads();
    }
    float4 bias;
    bias.x = bi[n0+tx*4+0] + bh[n0+tx*4+0];
    bias.y = bi[n0+tx*4+1] + bh[n0+tx*4+1];
    bias.z = bi[n0+tx*4+2] + bh[n0+tx*4+2];
    bias.w = bi[n0+tx*4+3] + bh[n0+tx*4+3];
    #pragma unroll
    for (int i = 0; i < 8; ++i) {
        int m = m0 + ty*8 + i;
        float4 v = { acc[i][0]+bias.x, acc[i][1]+bias.y,
                     acc[i][2]+bias.z, acc[i][3]+bias.w };
        *reinterpret_cast<float4*>(&Cout[(size_t)m*H_ + n0 + tx*4]) = v;
    }
}

// ------- recurrent scan, tagged-data sync ----------------------------------
// block = (pair p, slice s): batches {2p,2p+1}, rows [64s, 64s+64).
// LDS: Wt[512][64] (128KB) + hli[512][2] + red[2][4][64]. 137216B -> 1/CU.
#define ALOAD(p)  __hip_atomic_load((p),  __ATOMIC_RELAXED, __HIP_MEMORY_SCOPE_AGENT)
#define ASTORE(p,v) __hip_atomic_store((p),(v),__ATOMIC_RELAXED, __HIP_MEMORY_SCOPE_AGENT)

__global__ __launch_bounds__(256)
void rnn_scan_tag(const float* __restrict__ Whh, const float* __restrict__ xp,
                  float* __restrict__ hist, float* __restrict__ hlast,
                  unsigned long long* hxt, unsigned base, int Csteps)
{
    extern __shared__ float lds[];
    float* Wt  = lds;                  // [k][jl]  512*64
    float* hli = lds + 32768;          // [k][b]   512*2
    float* red = lds + 32768 + 1024;   // [b][kg][jl] 2*4*64

    const int tid = threadIdx.x;
    const int p   = blockIdx.x >> 3;
    const int s   = blockIdx.x & 7;
    const int b0  = p * 2;
    const int j0  = s * JS;

    // Stage W slice transposed (one-time; amortized over Csteps).
    for (int e = tid*4; e < JS*H_; e += 256*4) {
        int jl = e >> 9, k = e & 511;
        float4 w = *reinterpret_cast<const float4*>(&Whh[(size_t)(j0+jl)*H_ + k]);
        Wt[(k+0)*JS + jl] = w.x;  Wt[(k+1)*JS + jl] = w.y;
        Wt[(k+2)*JS + jl] = w.z;  Wt[(k+3)*JS + jl] = w.w;
    }
    if (base == 0)                         // t=0: h_0 = 0 (else lt=0 polls)
        for (int e = tid; e < 2*H_; e += 256) hli[e] = 0.f;
    __syncthreads();

    const int l    = tid & 63;
    const int kg   = tid >> 6;      // k-group wave 0..3 (k in [128kg,128kg+128))
    const int kb   = kg * 128;
    const int wb   = tid >> 6;      // tid<128: batch 0/1
    const int k_lo = kb + l;
    const int k_hi = kb + 64 + l;
    const bool full = ((s >> 1) != kg);  // wave-uniform: own slice outside range?

    for (int lt = 0; lt < Csteps; ++lt) {
        const unsigned tag_in = base + (unsigned)lt;   // tag of h_{t-1}
        const unsigned tagv   = tag_in + 1;            // tag of our output

        // xp prefetch (independent of poll; wait lands at use in phase B)
        float xpv = 0.f;
        if (tid < 128)
            xpv = xp[((size_t)(b0 + wb) * Csteps + lt) * H_ + j0 + l];

        // ---- phase A: poll-fill this wave's k-range, then dot ----
        if (tag_in != 0) {
            const unsigned long long* hx =
                hxt + ((size_t)(tag_in & 1) * B_ + b0) * H_;
            // lt==0 (fresh LDS): own-slice values are NOT in hli yet --
            // they're in hxt with tag==base from the previous launch.
            if (full || lt == 0) {
                unsigned long long v0, v1, v2, v3;
                for (;;) {
                    v0 = ALOAD(&hx[k_lo]);      v1 = ALOAD(&hx[k_hi]);
                    v2 = ALOAD(&hx[H_ + k_lo]); v3 = ALOAD(&hx[H_ + k_hi]);
                    if ((unsigned)(v0 >> 32) == tag_in &&
                        (unsigned)(v1 >> 32) == tag_in &&
                        (unsigned)(v2 >> 32) == tag_in &&
                        (unsigned)(v3 >> 32) == tag_in) break;
                }
                hli[k_lo*2+0] = __uint_as_float((unsigned)v0);
                hli[k_hi*2+0] = __uint_as_float((unsigned)v1);
                hli[k_lo*2+1] = __uint_as_float((unsigned)v2);
                hli[k_hi*2+1] = __uint_as_float((unsigned)v3);
            } else {
                // own slice self-filled last phase B; poll only the other
                const int ko = (s & 1) ? k_lo : k_hi;
                unsigned long long v0, v2;
                for (;;) {
                    v0 = ALOAD(&hx[ko]);  v2 = ALOAD(&hx[H_ + ko]);
                    if ((unsigned)(v0 >> 32) == tag_in &&
                        (unsigned)(v2 >> 32) == tag_in) break;
                }
                hli[ko*2+0] = __uint_as_float((unsigned)v0);
                hli[ko*2+1] = __uint_as_float((unsigned)v2);
            }
        }
        // dot: Wt reads 2-way bank alias (free); hli reads broadcast.
        float s00=0.f, s01=0.f, s10=0.f, s11=0.f;
        #pragma unroll 8
        for (int kk = 0; kk < 128; kk += 2) {
            int k = kb + kk;
            float w0 = Wt[(k+0)*JS + l];
            float w1 = Wt[(k+1)*JS + l];
            float2 h0 = *reinterpret_cast<const float2*>(&hli[(k+0)*2]);
            float2 h1 = *reinterpret_cast<const float2*>(&hli[(k+1)*2]);
            s00 += w0*h0.x;  s01 += w0*h0.y;
            s10 += w1*h1.x;  s11 += w1*h1.y;
        }
        red[(0*4 + kg)*64 + l] = s00 + s10;
        red[(1*4 + kg)*64 + l] = s01 + s11;
        __syncthreads();                                   // (1) red ready

        // ---- phase B: reduce + tanh + publish ----
        if (tid < 128) {
            float y = red[(wb*4+0)*64+l] + red[(wb*4+1)*64+l]
                    + red[(wb*4+2)*64+l] + red[(wb*4+3)*64+l] + xpv;
            float h = tanhf(y);
            if (hist)
                hist[((size_t)(b0 + wb) * Csteps + lt) * H_ + j0 + l] = h;
            if (hlast && lt == Csteps-1)
                hlast[(size_t)(b0 + wb) * H_ + j0 + l] = h;
            hli[(j0 + l)*2 + wb] = h;          // self-fill own slice
            unsigned long long pkt = ((unsigned long long)tagv << 32)
                                   | (unsigned long long)__float_as_uint(h);
            ASTORE(&hxt[((size_t)(tagv & 1) * B_ + b0 + wb) * H_ + j0 + l], pkt);
        }
        __syncthreads();               // (2) red WAR + self-fill visibility
    }
}

// ------- tiny FC head -----------------------------------------------------
__global__ __launch_bounds__(64)
void fc_kernel(const float* __restrict__ hl, const float* __restrict__ fw,
               const float* __restrict__ fb, float* __restrict__ out)
{
    int b = blockIdx.x, tid = threadIdx.x;
    float p0 = 0.f, p1 = 0.f;
    #pragma unroll
    for (int i = 0; i < 8; ++i) {
        int k = tid + i*64;
        float h = hl[(size_t)b*H_ + k];
        p0 += h * fw[k];
        p1 += h * fw[H_ + k];
    }
    #pragma unroll
    for (int off = 32; off > 0; off >>= 1) {
        p0 += __shfl_down(p0, off, 64);
        p1 += __shfl_down(p1, off, 64);
    }
    if (tid == 0) {
        out[b*2+0] = p0 + fb[0];
        out[b*2+1] = p1 + fb[1];
    }
}

extern "C" void kernel_launch(void* const* d_in, const int* in_sizes, int n_in,
                              void* d_out, int out_size, void* d_ws, size_t ws_size,
                              hipStream_t stream)
{
    const float* x    = (const float*)d_in[0];
    const float* Wih0 = (const float*)d_in[1];
    const float* Whh0 = (const float*)d_in[2];
    const float* bih0 = (const float*)d_in[3];
    const float* bhh0 = (const float*)d_in[4];
    const float* Wih1 = (const float*)d_in[5];
    const float* Whh1 = (const float*)d_in[6];
    const float* bih1 = (const float*)d_in[7];
    const float* bhh1 = (const float*)d_in[8];
    const float* fcW  = (const float*)d_in[9];
    const float* fcb  = (const float*)d_in[10];
    float* out = (float*)d_out;

    // ws-adaptive chunk size (ws_size constant per session -> graph-safe).
    const size_t EXTRA = 2u << 20;
    int C = 1024;
    while (C > 16 && (2*(size_t)C*131072 + EXTRA) > ws_size) C >>= 1;
    int lgC = 0; { int t = C; while (t > 1) { t >>= 1; ++lgC; } }

    char* ws = (char*)d_ws;
    size_t S = (size_t)C * 131072;
    float* P       = (float*)ws;          // xp0 then xp1 (per chunk)
    float* Hc      = (float*)(ws + S);    // h1 chunk
    char*  sm      = ws + 2*S;
    float* h2last  = (float*)sm;                                  // 128 KB
    unsigned long long* hxtA = (unsigned long long*)(sm + 131072);           // 512 KB
    unsigned long long* hxtB = (unsigned long long*)(sm + 131072 + 524288);  // 512 KB

    const int LDS_BYTES = (32768 + 1024 + 512) * 4;   // 137216 B -> 1 block/CU
    hipFuncSetAttribute(reinterpret_cast<const void*>(rnn_scan_tag),
                        hipFuncAttributeMaxDynamicSharedMemorySize, LDS_BYTES);

    // No memsets: tags are self-describing; 0xAA poison is an invalid tag.

    const int nch = T_ / C;
    for (int c = 0; c < nch; ++c) {
        const int t0 = c * C;
        // xp0 chunk = x[:, t0:t0+C, :] @ Wih0^T + bias
        proj_gemm<256><<<dim3(C/2, 8), 256, 0, stream>>>(x, Wih0, bih0, bhh0,
                                                         P, lgC, t0, T_);
        // layer-0 scan chunk -> h1 chunk (tags t0+1 .. t0+C in hxtA)
        rnn_scan_tag<<<256, 256, LDS_BYTES, stream>>>(Whh0, P, Hc, nullptr,
                                                      hxtA, (unsigned)t0, C);
        // xp1 chunk = h1chunk @ Wih1^T + bias (overwrites P)
        proj_gemm<512><<<dim3(C/2, 8), 256, 0, stream>>>(Hc, Wih1, bih1, bhh1,
                                                         P, lgC, 0, C);
        // layer-1 scan chunk; final h2 only on last chunk (tags in hxtB)
        rnn_scan_tag<<<256, 256, LDS_BYTES, stream>>>(Whh1, P, nullptr,
                                                      (c == nch-1) ? h2last : nullptr,
                                                      hxtB, (unsigned)t0, C);
    }
    fc_kernel<<<64, 64, 0, stream>>>(h2last, fcW, fcb, out);
}